// Round 1
// baseline (759.808 us; speedup 1.0000x reference)
//
#include <hip/hip_runtime.h>
#include <hip/hip_bf16.h>

typedef unsigned short bf_t;
typedef __attribute__((ext_vector_type(8))) short short8;
typedef __attribute__((ext_vector_type(4))) float f32x4;

#define B_ 8
#define H_ 16
#define N_ 1024
#define C_ 1152
#define HD 72
#define SCALE_F 0.11785113019775793f
#define EPS_F 1e-12f

typedef const __attribute__((address_space(1))) void* gas_p;
typedef __attribute__((address_space(3))) void* las_p;

__device__ inline bf_t f2bf(float f) {
  union { __hip_bfloat16 h; bf_t u; } cv;
  cv.h = __float2bfloat16(f);
  return cv.u;
}

__device__ inline void glds16(const bf_t* g, bf_t* l) {
  __builtin_amdgcn_global_load_lds((gas_p)g, (las_p)l, 16, 0, 0);
}

// ---------------- elementwise f32 -> bf16 cast ----------------
__global__ __launch_bounds__(256) void cast_bf16_k(const float* __restrict__ in,
                                                   bf_t* __restrict__ out, int n4) {
  int i = blockIdx.x * 256 + threadIdx.x;
  if (i < n4) {
    float4 v = reinterpret_cast<const float4*>(in)[i];
    ushort4 o;
    o.x = f2bf(v.x); o.y = f2bf(v.y); o.z = f2bf(v.z); o.w = f2bf(v.w);
    reinterpret_cast<ushort4*>(out)[i] = o;
  }
}

// ---------------- batched tiled transpose, f32[R][C] -> bf16[C][R] ----------------
__global__ __launch_bounds__(256) void transpose_cast_k(const float* __restrict__ in,
                                                        bf_t* __restrict__ out, int R, int C) {
  __shared__ float t[32][33];
  const size_t bo = (size_t)blockIdx.z * R * C;
  const int tx = threadIdx.x, ty = threadIdx.y;
  const int r0 = blockIdx.y * 32, c0 = blockIdx.x * 32;
#pragma unroll
  for (int i = 0; i < 4; ++i) {
    int r = r0 + ty + i * 8, c = c0 + tx;
    if (r < R && c < C) t[ty + i * 8][tx] = in[bo + (size_t)r * C + c];
  }
  __syncthreads();
#pragma unroll
  for (int i = 0; i < 4; ++i) {
    int c = c0 + ty + i * 8, r = r0 + tx;
    if (r < R && c < C) out[bo + (size_t)c * R + r] = f2bf(t[tx][ty + i * 8]);
  }
}

// ---------------- GEMM: C = A[M][K] * Bt[N][K]^T, m97-style ----------------
// EPI 0: QKV epilogue (split q/k/v, +bias, q*=SCALE, v transposed), EPI 1: proj (+bias, f32 out)
template <int EPI>
__global__ __launch_bounds__(256) void gemm_bt_k(
    const bf_t* __restrict__ A, const bf_t* __restrict__ Bt,
    const float* __restrict__ bias, int K,
    bf_t* __restrict__ q_out, bf_t* __restrict__ k_out, bf_t* __restrict__ vT_out,
    float* __restrict__ f_out, int ldc) {
  __shared__ bf_t Alds[128 * 32];
  __shared__ bf_t Blds[128 * 32];
  const int tid = threadIdx.x, lane = tid & 63, wave = tid >> 6;
  const int l15 = lane & 15, l4 = lane >> 4;
  const int m0 = blockIdx.x * 128, n0 = blockIdx.y * 128;
  const int wr = (wave >> 1) * 64, wc = (wave & 1) * 64;

  f32x4 acc[4][4] = {};

  for (int k0 = 0; k0 < K; k0 += 32) {
#pragma unroll
    for (int cc = 0; cc < 2; ++cc) {
      const int c = 2 * wave + cc;
      const int idx = c * 512 + lane * 8;
      const int row = idx >> 5, col = idx & 31;
      glds16(A + (size_t)(m0 + row) * K + k0 + col, Alds + c * 512);
      glds16(Bt + (size_t)(n0 + row) * K + k0 + col, Blds + c * 512);
    }
    __syncthreads();
    short8 a[4], b[4];
#pragma unroll
    for (int i = 0; i < 4; ++i)
      a[i] = *reinterpret_cast<const short8*>(Alds + (wr + i * 16 + l15) * 32 + l4 * 8);
#pragma unroll
    for (int j = 0; j < 4; ++j)
      b[j] = *reinterpret_cast<const short8*>(Blds + (wc + j * 16 + l15) * 32 + l4 * 8);
#pragma unroll
    for (int i = 0; i < 4; ++i)
#pragma unroll
      for (int j = 0; j < 4; ++j)
        acc[i][j] = __builtin_amdgcn_mfma_f32_16x16x32_bf16(a[i], b[j], acc[i][j], 0, 0, 0);
    __syncthreads();
  }

#pragma unroll
  for (int j = 0; j < 4; ++j) {
    const int n = n0 + wc + j * 16 + l15;
    const float bn = bias[n];
    if constexpr (EPI == 0) {
      const int sec = n / C_;
      const int rem = n - sec * C_;
      const int h = rem / HD;
      const int d = rem - h * HD;
#pragma unroll
      for (int i = 0; i < 4; ++i)
#pragma unroll
        for (int r = 0; r < 4; ++r) {
          const int m = m0 + wr + i * 16 + l4 * 4 + r;
          const int bb = m >> 10, t = m & 1023;
          const float v = acc[i][j][r] + bn;
          const size_t bh = (size_t)(bb * H_ + h);
          if (sec == 0)      q_out[(bh * N_ + t) * HD + d] = f2bf(v * SCALE_F);
          else if (sec == 1) k_out[(bh * N_ + t) * HD + d] = f2bf(v);
          else               vT_out[(bh * HD + d) * N_ + t] = f2bf(v);
        }
    } else {
#pragma unroll
      for (int i = 0; i < 4; ++i)
#pragma unroll
        for (int r = 0; r < 4; ++r) {
          const int m = m0 + wr + i * 16 + l4 * 4 + r;
          f_out[(size_t)m * ldc + n] = acc[i][j][r] + bn;
        }
    }
  }
}

// ---------------- fused dual-stream flash attention + distill losses ----------------
// grid: (128 bh, 16 q-tiles); block 256 (4 waves, 16 q-rows each)
__global__ __launch_bounds__(256) void attn_k(
    const bf_t* __restrict__ q, const bf_t* __restrict__ ks, const bf_t* __restrict__ kd,
    const bf_t* __restrict__ vsT, const bf_t* __restrict__ vdT,
    bf_t* __restrict__ attn_out, float* __restrict__ loss_acc) {
  // padded row strides: 104 elems (208B) and 72 elems (144B) -> <=2-way bank conflicts
  __shared__ bf_t Qs[64][104];
  __shared__ bf_t Ksl[64][104];
  __shared__ bf_t Kdl[64][104];
  __shared__ bf_t Vsl[80][72];
  __shared__ bf_t Vdl[80][72];
  __shared__ bf_t Pl[4][16][72];

  const int tid = threadIdx.x, lane = tid & 63, wave = tid >> 6;
  const int l15 = lane & 15, l4 = lane >> 4;
  const int bh = blockIdx.x;
  const int q0 = blockIdx.y * 64;
  const int bb = bh >> 4, h = bh & 15;

  // stage Q tile once (zero-pad head dim 72 -> 96; cols 96..103 never read)
  for (int g = tid; g < 64 * 13; g += 256) {
    const int row = g / 13, cg = g % 13;
    short8 v = {};
    if (cg < 9) v = *reinterpret_cast<const short8*>(q + ((size_t)bh * N_ + q0 + row) * HD + cg * 8);
    *reinterpret_cast<short8*>(&Qs[row][cg * 8]) = v;
  }

  f32x4 S[2][4];
  f32x4 O[2][5] = {};
  f32x4 mrun[2], lrun[2], ssum, dsum, xsum;
#pragma unroll
  for (int r = 0; r < 4; ++r) {
    mrun[0][r] = -INFINITY; mrun[1][r] = -INFINITY;
    lrun[0][r] = 0.f; lrun[1][r] = 0.f;
    ssum[r] = 0.f; dsum[r] = 0.f; xsum[r] = 0.f;
  }

  for (int kt = 0; kt < 16; ++kt) {
    const int m0 = kt * 64;
    __syncthreads();  // protect LDS from previous iteration's readers
    for (int g = tid; g < 64 * 13; g += 256) {
      const int row = g / 13, cg = g % 13;
      short8 vs = {}, vd = {};
      if (cg < 9) {
        const size_t go = ((size_t)bh * N_ + m0 + row) * HD + cg * 8;
        vs = *reinterpret_cast<const short8*>(ks + go);
        vd = *reinterpret_cast<const short8*>(kd + go);
      }
      *reinterpret_cast<short8*>(&Ksl[row][cg * 8]) = vs;
      *reinterpret_cast<short8*>(&Kdl[row][cg * 8]) = vd;
    }
    for (int g = tid; g < 80 * 9; g += 256) {
      const int d = g / 9, cg = g % 9;
      short8 vs = {}, vd = {};
      if (d < HD && cg < 8) {
        const size_t go = ((size_t)bh * HD + d) * N_ + m0 + cg * 8;
        vs = *reinterpret_cast<const short8*>(vsT + go);
        vd = *reinterpret_cast<const short8*>(vdT + go);
      }
      *reinterpret_cast<short8*>(&Vsl[d][cg * 8]) = vs;
      *reinterpret_cast<short8*>(&Vdl[d][cg * 8]) = vd;
    }
    __syncthreads();

    // QK^T, both streams (q pre-scaled by SCALE)
#pragma unroll
    for (int j = 0; j < 4; ++j) {
      f32x4 z = {0.f, 0.f, 0.f, 0.f};
      S[0][j] = z; S[1][j] = z;
    }
#pragma unroll
    for (int ksp = 0; ksp < 3; ++ksp) {
      const short8 aq = *reinterpret_cast<const short8*>(&Qs[wave * 16 + l15][ksp * 32 + l4 * 8]);
#pragma unroll
      for (int j = 0; j < 4; ++j) {
        const short8 b0 = *reinterpret_cast<const short8*>(&Ksl[j * 16 + l15][ksp * 32 + l4 * 8]);
        S[0][j] = __builtin_amdgcn_mfma_f32_16x16x32_bf16(aq, b0, S[0][j], 0, 0, 0);
        const short8 b1 = *reinterpret_cast<const short8*>(&Kdl[j * 16 + l15][ksp * 32 + l4 * 8]);
        S[1][j] = __builtin_amdgcn_mfma_f32_16x16x32_bf16(aq, b1, S[1][j], 0, 0, 0);
      }
    }

    // logit-loss partials (per-lane partial row sums)
#pragma unroll
    for (int j = 0; j < 4; ++j)
#pragma unroll
      for (int r = 0; r < 4; ++r) {
        ssum[r] += S[0][j][r] * S[0][j][r];
        dsum[r] += S[1][j][r] * S[1][j][r];
        xsum[r] += S[0][j][r] * S[1][j][r];
      }

    // per stream: online softmax + PV
#pragma unroll
    for (int s = 0; s < 2; ++s) {
      f32x4 tmax;
#pragma unroll
      for (int r = 0; r < 4; ++r) {
        float t = fmaxf(fmaxf(S[s][0][r], S[s][1][r]), fmaxf(S[s][2][r], S[s][3][r]));
        t = fmaxf(t, __shfl_xor(t, 1));
        t = fmaxf(t, __shfl_xor(t, 2));
        t = fmaxf(t, __shfl_xor(t, 4));
        t = fmaxf(t, __shfl_xor(t, 8));
        tmax[r] = t;
      }
      f32x4 fac;
#pragma unroll
      for (int r = 0; r < 4; ++r) {
        const float nm = fmaxf(mrun[s][r], tmax[r]);
        fac[r] = __expf(mrun[s][r] - nm);
        mrun[s][r] = nm;
        lrun[s][r] *= fac[r];
      }
#pragma unroll
      for (int f = 0; f < 5; ++f)
#pragma unroll
        for (int r = 0; r < 4; ++r) O[s][f][r] *= fac[r];

      asm volatile("s_waitcnt lgkmcnt(0)" ::: "memory");  // prior PV reads of Pl done
#pragma unroll
      for (int j = 0; j < 4; ++j)
#pragma unroll
        for (int r = 0; r < 4; ++r) {
          const float p = __expf(S[s][j][r] - mrun[s][r]);
          lrun[s][r] += p;
          Pl[wave][l4 * 4 + r][j * 16 + l15] = f2bf(p);
        }
      asm volatile("s_waitcnt lgkmcnt(0)" ::: "memory");  // P writes visible

      const bf_t* Vp = (s == 0) ? &Vsl[0][0] : &Vdl[0][0];
#pragma unroll
      for (int k2 = 0; k2 < 2; ++k2) {
        const short8 ap = *reinterpret_cast<const short8*>(&Pl[wave][l15][k2 * 32 + l4 * 8]);
#pragma unroll
        for (int f = 0; f < 5; ++f) {
          const short8 bv = *reinterpret_cast<const short8*>(Vp + (f * 16 + l15) * HD + k2 * 32 + l4 * 8);
          O[s][f] = __builtin_amdgcn_mfma_f32_16x16x32_bf16(ap, bv, O[s][f], 0, 0, 0);
        }
      }
    }
  }

  auto red16 = [](float v) {
    v += __shfl_xor(v, 1); v += __shfl_xor(v, 2);
    v += __shfl_xor(v, 4); v += __shfl_xor(v, 8);
    return v;
  };

  float contrib = 0.f;
#pragma unroll
  for (int r = 0; r < 4; ++r) {
    const float ls = red16(lrun[0][r]);
    const float ld = red16(lrun[1][r]);
    lrun[0][r] = ls; lrun[1][r] = ld;
    const float ssR = red16(ssum[r]);
    const float ddR = red16(dsum[r]);
    const float sdR = red16(xsum[r]);
    float paa = 0.f, pbb = 0.f, pab = 0.f;
#pragma unroll
    for (int f = 0; f < 5; ++f) {
      paa += O[0][f][r] * O[0][f][r];
      pbb += O[1][f][r] * O[1][f][r];
      pab += O[0][f][r] * O[1][f][r];
    }
    const float aaR = red16(paa);
    const float bbR = red16(pbb);
    const float abR = red16(pab);
    const float cosL = sdR / (fmaxf(sqrtf(ssR), EPS_F) * fmaxf(sqrtf(ddR), EPS_F));
    const float cosA = abR / (fmaxf(sqrtf(aaR), EPS_F) * fmaxf(sqrtf(bbR), EPS_F));
    contrib += cosL + 0.5f * cosA;
  }
  if (l15 == 0) atomicAdd(loss_acc, contrib);

  // write attn_sit (normalized) as bf16 [token][h*72+d]
#pragma unroll
  for (int f = 0; f < 5; ++f) {
    const int d = f * 16 + l15;
    if (d < HD) {
#pragma unroll
      for (int r = 0; r < 4; ++r) {
        const int row = q0 + wave * 16 + l4 * 4 + r;
        const float v = O[0][f][r] / lrun[0][r];
        attn_out[(size_t)(bb * N_ + row) * C_ + h * HD + d] = f2bf(v);
      }
    }
  }
}

__global__ void finalize_k(const float* __restrict__ acc, float* __restrict__ out) {
  if (threadIdx.x == 0)
    out[(size_t)B_ * N_ * C_] = 1.5f - acc[0] * (1.0f / 131072.0f);
}

extern "C" void kernel_launch(void* const* d_in, const int* in_sizes, int n_in,
                              void* d_out, int out_size, void* d_ws, size_t ws_size,
                              hipStream_t stream) {
  const float* x      = (const float*)d_in[0];
  const float* k_dino = (const float*)d_in[1];
  const float* v_dino = (const float*)d_in[2];
  const float* W_qkv  = (const float*)d_in[3];
  const float* b_qkv  = (const float*)d_in[4];
  const float* W_proj = (const float*)d_in[5];
  const float* b_proj = (const float*)d_in[6];
  float* out = (float*)d_out;

  char* p = (char*)d_ws;
  auto alloc = [&](size_t bytes) {
    char* r = p;
    p += (bytes + 255) & ~(size_t)255;
    return r;
  };
  const size_t EL = (size_t)B_ * N_ * C_;  // 9437184
  bf_t* x_bf   = (bf_t*)alloc(EL * 2);
  bf_t* q_bf   = (bf_t*)alloc(EL * 2);
  bf_t* ks_bf  = (bf_t*)alloc(EL * 2);
  bf_t* kd_bf  = (bf_t*)alloc(EL * 2);
  bf_t* vsT_bf = (bf_t*)alloc(EL * 2);
  bf_t* vdT_bf = (bf_t*)alloc(EL * 2);
  bf_t* wqkvT  = (bf_t*)alloc((size_t)C_ * 3 * C_ * 2);
  bf_t* wprojT = (bf_t*)alloc((size_t)C_ * C_ * 2);
  float* loss  = (float*)alloc(256);
  bf_t* attn_bf = x_bf;  // alias: x_bf dead after QKV GEMM

  hipMemsetAsync(loss, 0, 4, stream);
  cast_bf16_k<<<dim3((unsigned)(EL / 4 / 256)), 256, 0, stream>>>(x, x_bf, (int)(EL / 4));
  cast_bf16_k<<<dim3((unsigned)(EL / 4 / 256)), 256, 0, stream>>>(k_dino, kd_bf, (int)(EL / 4));
  transpose_cast_k<<<dim3(108, 36, 1), dim3(32, 8), 0, stream>>>(W_qkv, wqkvT, 1152, 3456);
  transpose_cast_k<<<dim3(36, 36, 1), dim3(32, 8), 0, stream>>>(W_proj, wprojT, 1152, 1152);
  transpose_cast_k<<<dim3(3, 32, 128), dim3(32, 8), 0, stream>>>(v_dino, vdT_bf, 1024, 72);
  gemm_bt_k<0><<<dim3(64, 27), 256, 0, stream>>>(x_bf, wqkvT, b_qkv, C_, q_bf, ks_bf, vsT_bf, nullptr, 0);
  attn_k<<<dim3(128, 16), 256, 0, stream>>>(q_bf, ks_bf, kd_bf, vsT_bf, vdT_bf, attn_bf, loss);
  gemm_bt_k<1><<<dim3(64, 9), 256, 0, stream>>>(attn_bf, wprojT, b_proj, C_, nullptr, nullptr, nullptr, out, C_);
  finalize_k<<<1, 64, 0, stream>>>(loss, out);
}

// Round 8
// 621.623 us; speedup vs baseline: 1.2223x; 1.2223x over previous
//
#include <hip/hip_runtime.h>
#include <hip/hip_bf16.h>

typedef unsigned short bf_t;
typedef __attribute__((ext_vector_type(8))) short short8;
typedef __attribute__((ext_vector_type(4))) float f32x4;

#define B_ 8
#define H_ 16
#define N_ 1024
#define C_ 1152
#define HD 72
#define SCALE_F 0.11785113019775793f
#define QSC_F (SCALE_F * 1.4426950408889634f)  // fold log2(e): exp -> exp2
#define EPS_F 1e-12f

typedef const __attribute__((address_space(1))) void* gas_p;
typedef __attribute__((address_space(3))) void* las_p;

__device__ inline bf_t f2bf(float f) {
  union { __hip_bfloat16 h; bf_t u; } cv;
  cv.h = __float2bfloat16(f);
  return cv.u;
}

__device__ inline void glds16(const bf_t* g, bf_t* l) {
  __builtin_amdgcn_global_load_lds((gas_p)g, (las_p)l, 16, 0, 0);
}

__device__ inline f32x4 mfma32(short8 a, short8 b, f32x4 c) {
  return __builtin_amdgcn_mfma_f32_16x16x32_bf16(a, b, c, 0, 0, 0);
}

// ---------------- elementwise f32 -> bf16 cast ----------------
__global__ __launch_bounds__(256) void cast_bf16_k(const float* __restrict__ in,
                                                   bf_t* __restrict__ out, int n4) {
  int i = blockIdx.x * 256 + threadIdx.x;
  if (i < n4) {
    float4 v = reinterpret_cast<const float4*>(in)[i];
    ushort4 o;
    o.x = f2bf(v.x); o.y = f2bf(v.y); o.z = f2bf(v.z); o.w = f2bf(v.w);
    reinterpret_cast<ushort4*>(out)[i] = o;
  }
}

// ---------------- batched tiled transpose, f32[R][C] -> bf16[C][R] ----------------
__global__ __launch_bounds__(256) void transpose_cast_k(const float* __restrict__ in,
                                                        bf_t* __restrict__ out, int R, int C) {
  __shared__ float t[32][33];
  const size_t bo = (size_t)blockIdx.z * R * C;
  const int tx = threadIdx.x, ty = threadIdx.y;
  const int r0 = blockIdx.y * 32, c0 = blockIdx.x * 32;
#pragma unroll
  for (int i = 0; i < 4; ++i) {
    int r = r0 + ty + i * 8, c = c0 + tx;
    if (r < R && c < C) t[ty + i * 8][tx] = in[bo + (size_t)r * C + c];
  }
  __syncthreads();
#pragma unroll
  for (int i = 0; i < 4; ++i) {
    int c = c0 + ty + i * 8, r = r0 + tx;
    if (r < R && c < C) out[bo + (size_t)c * R + r] = f2bf(t[tx][ty + i * 8]);
  }
}

// ---------------- GEMM: C = A[M][K] * Bt[N][K]^T, m97-style ----------------
template <int EPI>
__global__ __launch_bounds__(256) void gemm_bt_k(
    const bf_t* __restrict__ A, const bf_t* __restrict__ Bt,
    const float* __restrict__ bias, int K,
    bf_t* __restrict__ q_out, bf_t* __restrict__ k_out, bf_t* __restrict__ vT_out,
    float* __restrict__ f_out, int ldc) {
  __shared__ bf_t Alds[128 * 32];
  __shared__ bf_t Blds[128 * 32];
  const int tid = threadIdx.x, lane = tid & 63, wave = tid >> 6;
  const int l15 = lane & 15, l4 = lane >> 4;
  const int m0 = blockIdx.x * 128, n0 = blockIdx.y * 128;
  const int wr = (wave >> 1) * 64, wc = (wave & 1) * 64;

  f32x4 acc[4][4] = {};

  for (int k0 = 0; k0 < K; k0 += 32) {
#pragma unroll
    for (int cc = 0; cc < 2; ++cc) {
      const int c = 2 * wave + cc;
      const int idx = c * 512 + lane * 8;
      const int row = idx >> 5, col = idx & 31;
      glds16(A + (size_t)(m0 + row) * K + k0 + col, Alds + c * 512);
      glds16(Bt + (size_t)(n0 + row) * K + k0 + col, Blds + c * 512);
    }
    __syncthreads();
    short8 a[4], b[4];
#pragma unroll
    for (int i = 0; i < 4; ++i)
      a[i] = *reinterpret_cast<const short8*>(Alds + (wr + i * 16 + l15) * 32 + l4 * 8);
#pragma unroll
    for (int j = 0; j < 4; ++j)
      b[j] = *reinterpret_cast<const short8*>(Blds + (wc + j * 16 + l15) * 32 + l4 * 8);
#pragma unroll
    for (int i = 0; i < 4; ++i)
#pragma unroll
      for (int j = 0; j < 4; ++j)
        acc[i][j] = mfma32(a[i], b[j], acc[i][j]);
    __syncthreads();
  }

#pragma unroll
  for (int j = 0; j < 4; ++j) {
    const int n = n0 + wc + j * 16 + l15;
    const float bn = bias[n];
    if constexpr (EPI == 0) {
      const int sec = n / C_;
      const int rem = n - sec * C_;
      const int h = rem / HD;
      const int d = rem - h * HD;
#pragma unroll
      for (int i = 0; i < 4; ++i)
#pragma unroll
        for (int r = 0; r < 4; ++r) {
          const int m = m0 + wr + i * 16 + l4 * 4 + r;
          const int bb = m >> 10, t = m & 1023;
          const float v = acc[i][j][r] + bn;
          const size_t bh = (size_t)(bb * H_ + h);
          if (sec == 0)      q_out[(bh * N_ + t) * HD + d] = f2bf(v * QSC_F);
          else if (sec == 1) k_out[(bh * N_ + t) * HD + d] = f2bf(v);
          else               vT_out[(bh * HD + d) * N_ + t] = f2bf(v);
        }
    } else {
#pragma unroll
      for (int i = 0; i < 4; ++i)
#pragma unroll
        for (int r = 0; r < 4; ++r) {
          const int m = m0 + wr + i * 16 + l4 * 4 + r;
          f_out[(size_t)m * ldc + n] = acc[i][j][r] + bn;
        }
    }
  }
}

// ---------------- fused dual-stream flash attention + distill losses ----------------
// grid: (16 q-tiles, 128 bh); block 256 (4 waves, 16 q-rows each).
// Swapped QK^T (S^T = mfma(K,Q)): lane owns q-row = l15; kpos = j*16 + l4*4 + r.
// PV: P -> wave-private LDS tile [16][72] -> standard mfma32 A-fragment (r1-proven).
// V: round-1 geometry — linear [80][72] d-major, manually reg-staged, rows 72..79
// zeroed (r1-proven read: Vp[(f*16+l15)*72 + k2*32 + l4*8]). NO swizzle (bisection).
// K: glds16 linear [64][72] (gemm-proven pattern); tail k=64..95 via third mfma32,
// Q tail frag zero except l4==0 -> k>=72 products annihilate.
__global__ __launch_bounds__(256, 3) void attn_k(
    const bf_t* __restrict__ q, const bf_t* __restrict__ ks, const bf_t* __restrict__ kd,
    const bf_t* __restrict__ vsT, const bf_t* __restrict__ vdT,
    bf_t* __restrict__ attn_out, float* __restrict__ loss_acc) {
  __shared__ __align__(16) bf_t SM[25344];
  bf_t* Ksl = SM;            // [64][72] linear
  bf_t* Kdl = SM + 4608;
  bf_t* Vsl = SM + 9216;     // [80][72], rows 72..79 zeroed
  bf_t* Vdl = SM + 14976;
  bf_t* Plb = SM + 20736;    // [4 waves][16][72]

  const int tid = threadIdx.x, lane = tid & 63, wave = tid >> 6;
  const int l15 = lane & 15, l4 = lane >> 4;
  const int q0 = blockIdx.x * 64;
  const int bh = blockIdx.y;
  const int bb = bh >> 4, h = bh & 15;
  bf_t* Plp = Plb + wave * 1152;

  // Q in registers (B-fragment: col=q=l15, k = ksp*32 + l4*8 + t).
  const int qrow = q0 + wave * 16 + l15;
  const bf_t* qp = q + ((size_t)bh * N_ + qrow) * HD;
  const short8 aq0 = *reinterpret_cast<const short8*>(qp + l4 * 8);
  const short8 aq1 = *reinterpret_cast<const short8*>(qp + 32 + l4 * 8);
  short8 aq2 = {};                       // k = 64..95: only l4==0 (k=64..71) is real
  if (l4 == 0) aq2 = *reinterpret_cast<const short8*>(qp + 64);

  // zero V pad rows 72..79, cols 0..63 (read range), once
  {
    const short8 z = {};
    for (int g = tid; g < 128; g += 256) {
      const int s = g >= 64;
      const int i = g - s * 64;
      *reinterpret_cast<short8*>((s ? Vdl : Vsl) + (72 + (i >> 3)) * 72 + (i & 7) * 8) = z;
    }
  }

  auto stage = [&](int m0) {
    const size_t kbase = ((size_t)bh * N_ + m0) * HD;
    for (int cc = wave; cc < 18; cc += 4) {       // K: glds16 linear copy
      const int arr = (cc >= 9);
      const int c = cc - (arr ? 9 : 0);
      glds16((arr ? kd : ks) + kbase + c * 512 + lane * 8, (arr ? Kdl : Ksl) + c * 512);
    }
    for (int g = tid; g < 1152; g += 256) {       // V: manual reg-staged, linear [d][kp]
      const int s = g >= 576;
      const int i = g - s * 576;
      const int row = i >> 3, cg = i & 7;
      const short8 v = *reinterpret_cast<const short8*>(
          (s ? vdT : vsT) + ((size_t)bh * HD + row) * N_ + m0 + cg * 8);
      *reinterpret_cast<short8*>((s ? Vdl : Vsl) + row * 72 + cg * 8) = v;
    }
  };

  f32x4 O0[5] = {}, O1[5] = {};
  float m0s = -INFINITY, m1s = -INFINITY, l0s = 0.f, l1s = 0.f;
  float ss = 0.f, dd = 0.f, xx = 0.f;

  stage(0);

  // rescale running state (always-rescale; no defer)
  auto rescale = [&](f32x4 (&S)[4], f32x4 (&O)[5], float& m, float& l) {
    float t = fmaxf(fmaxf(fmaxf(S[0][0], S[0][1]), fmaxf(S[0][2], S[0][3])),
                    fmaxf(fmaxf(S[1][0], S[1][1]), fmaxf(S[1][2], S[1][3])));
    t = fmaxf(t, fmaxf(fmaxf(fmaxf(S[2][0], S[2][1]), fmaxf(S[2][2], S[2][3])),
                       fmaxf(fmaxf(S[3][0], S[3][1]), fmaxf(S[3][2], S[3][3]))));
    t = fmaxf(t, __shfl_xor(t, 16));
    t = fmaxf(t, __shfl_xor(t, 32));
    const float nm = fmaxf(m, t);
    const float fac = __builtin_amdgcn_exp2f(m - nm);
    m = nm; l *= fac;
    float fT[4];
#pragma unroll
    for (int r = 0; r < 4; ++r) fT[r] = __shfl(fac, (l4 * 4 + r) | (l4 << 4));
#pragma unroll
    for (int f = 0; f < 5; ++f)
#pragma unroll
      for (int r = 0; r < 4; ++r) O[f][r] *= fT[r];
  };

  // exp + write P tile to wave-private LDS (Pl[q=l15][kpos])
  auto write_P = [&](f32x4 (&S)[4], float m, float& l) {
#pragma unroll
    for (int j = 0; j < 4; ++j) {
      const float p0 = __builtin_amdgcn_exp2f(S[j][0] - m);
      const float p1 = __builtin_amdgcn_exp2f(S[j][1] - m);
      const float p2 = __builtin_amdgcn_exp2f(S[j][2] - m);
      const float p3 = __builtin_amdgcn_exp2f(S[j][3] - m);
      l += (p0 + p1) + (p2 + p3);
      union { __hip_bfloat162 h; unsigned u; } lo, hi;
      lo.h = __float22bfloat162_rn(make_float2(p0, p1));
      hi.h = __float22bfloat162_rn(make_float2(p2, p3));
      uint2 w; w.x = lo.u; w.y = hi.u;
      *reinterpret_cast<uint2*>(Plp + l15 * 72 + j * 16 + l4 * 4) = w;
    }
  };

  auto pv = [&](f32x4 (&O)[5], const bf_t* Vp) {
#pragma unroll
    for (int k2 = 0; k2 < 2; ++k2) {
      const short8 ap = *reinterpret_cast<const short8*>(Plp + l15 * 72 + k2 * 32 + l4 * 8);
#pragma unroll
      for (int f = 0; f < 5; ++f) {
        const short8 bv = *reinterpret_cast<const short8*>(
            Vp + (f * 16 + l15) * HD + k2 * 32 + l4 * 8);
        O[f] = mfma32(ap, bv, O[f]);
      }
    }
  };

#pragma unroll 1
  for (int kt = 0; kt < 16; ++kt) {
    __syncthreads();  // drains vmcnt (glds) + lgkm; joins all waves

    // ---- dual QK^T (S^T = K_tile . Q^T), 3 k-steps of 32 ----
    f32x4 S0[4] = {}, S1[4] = {};
#pragma unroll
    for (int ksp = 0; ksp < 2; ++ksp) {
      const short8 qf = ksp ? aq1 : aq0;
#pragma unroll
      for (int j = 0; j < 4; ++j) {
        const int ko = (j * 16 + l15) * HD + ksp * 32 + l4 * 8;
        S0[j] = mfma32(*reinterpret_cast<const short8*>(Ksl + ko), qf, S0[j]);
        S1[j] = mfma32(*reinterpret_cast<const short8*>(Kdl + ko), qf, S1[j]);
      }
    }
#pragma unroll
    for (int j = 0; j < 4; ++j) {  // k=64..95 tail; aq2 zero for l4>=1 kills k>=72
      const int ko = (j * 16 + l15) * HD + 64 + l4 * 8;
      S0[j] = mfma32(*reinterpret_cast<const short8*>(Ksl + ko), aq2, S0[j]);
      S1[j] = mfma32(*reinterpret_cast<const short8*>(Kdl + ko), aq2, S1[j]);
    }

    // logit-align partials (per-lane; scale-invariant under log2e folding)
#pragma unroll
    for (int j = 0; j < 4; ++j)
#pragma unroll
      for (int r = 0; r < 4; ++r) {
        ss += S0[j][r] * S0[j][r];
        dd += S1[j][r] * S1[j][r];
        xx += S0[j][r] * S1[j][r];
      }

    // ---- stream 0: softmax + PV ----
    rescale(S0, O0, m0s, l0s);
    asm volatile("s_waitcnt lgkmcnt(0)" ::: "memory");  // prior Pl reads done (WAR)
    write_P(S0, m0s, l0s);
    asm volatile("s_waitcnt lgkmcnt(0)" ::: "memory");  // P visible (RAW)
    pv(O0, Vsl);

    // ---- stream 1: softmax + PV ----
    rescale(S1, O1, m1s, l1s);
    asm volatile("s_waitcnt lgkmcnt(0)" ::: "memory");
    write_P(S1, m1s, l1s);
    asm volatile("s_waitcnt lgkmcnt(0)" ::: "memory");
    pv(O1, Vdl);

    __syncthreads();
    if (kt < 15) stage((kt + 1) * 64);
  }

  auto red16 = [](float v) {  // sum across l15 group
    v += __shfl_xor(v, 1); v += __shfl_xor(v, 2);
    v += __shfl_xor(v, 4); v += __shfl_xor(v, 8);
    return v;
  };
  auto redL4 = [](float v) {  // sum across l4 group
    v += __shfl_xor(v, 16); v += __shfl_xor(v, 32);
    return v;
  };

  // logit-align cos per q (l15 layout)
  const float ssT = redL4(ss), ddT = redL4(dd), xxT = redL4(xx);
  const float lsT = redL4(l0s);
  const float cosL = xxT / (fmaxf(sqrtf(ssT), EPS_F) * fmaxf(sqrtf(ddT), EPS_F));
  const float sumL = red16(cosL);

  // attn-align cos per q (l4*4+r layout); mask d>=72 (f==4, l15>=8)
  float sumA = 0.f;
#pragma unroll
  for (int r = 0; r < 4; ++r) {
    float aa = 0.f, bb2 = 0.f, ab = 0.f;
#pragma unroll
    for (int f = 0; f < 5; ++f) {
      const float w = (f < 4 || l15 < 8) ? 1.f : 0.f;
      const float a = O0[f][r], b = O1[f][r];
      aa += w * a * a; bb2 += w * b * b; ab += w * a * b;
    }
    aa = red16(aa); bb2 = red16(bb2); ab = red16(ab);
    sumA += ab / (fmaxf(sqrtf(aa), EPS_F) * fmaxf(sqrtf(bb2), EPS_F));
  }
  sumA = redL4(sumA);

  if (lane == 0) atomicAdd(loss_acc, sumL + 0.5f * sumA);

  // write attn_sit / l (bf16, [b][n][h*72+d])
  float lT[4];
#pragma unroll
  for (int r = 0; r < 4; ++r) lT[r] = __shfl(lsT, (l4 * 4 + r) | (l4 << 4));
#pragma unroll
  for (int f = 0; f < 5; ++f) {
    const int d = f * 16 + l15;
    if (d < HD) {
#pragma unroll
      for (int r = 0; r < 4; ++r) {
        const int row = q0 + wave * 16 + l4 * 4 + r;
        attn_out[(size_t)(bb * N_ + row) * C_ + h * HD + d] = f2bf(O0[f][r] / lT[r]);
      }
    }
  }
}

__global__ void finalize_k(const float* __restrict__ acc, float* __restrict__ out) {
  if (threadIdx.x == 0)
    out[(size_t)B_ * N_ * C_] = 1.5f - acc[0] * (1.0f / 131072.0f);
}

extern "C" void kernel_launch(void* const* d_in, const int* in_sizes, int n_in,
                              void* d_out, int out_size, void* d_ws, size_t ws_size,
                              hipStream_t stream) {
  const float* x      = (const float*)d_in[0];
  const float* k_dino = (const float*)d_in[1];
  const float* v_dino = (const float*)d_in[2];
  const float* W_qkv  = (const float*)d_in[3];
  const float* b_qkv  = (const float*)d_in[4];
  const float* W_proj = (const float*)d_in[5];
  const float* b_proj = (const float*)d_in[6];
  float* out = (float*)d_out;

  char* p = (char*)d_ws;
  auto alloc = [&](size_t bytes) {
    char* r = p;
    p += (bytes + 255) & ~(size_t)255;
    return r;
  };
  const size_t EL = (size_t)B_ * N_ * C_;  // 9437184
  bf_t* x_bf   = (bf_t*)alloc(EL * 2);
  bf_t* q_bf   = (bf_t*)alloc(EL * 2);
  bf_t* ks_bf  = (bf_t*)alloc(EL * 2);
  bf_t* kd_bf  = (bf_t*)alloc(EL * 2);
  bf_t* vsT_bf = (bf_t*)alloc(EL * 2);
  bf_t* vdT_bf = (bf_t*)alloc(EL * 2);
  bf_t* wqkvT  = (bf_t*)alloc((size_t)C_ * 3 * C_ * 2);
  bf_t* wprojT = (bf_t*)alloc((size_t)C_ * C_ * 2);
  float* loss  = (float*)alloc(256);
  bf_t* attn_bf = x_bf;  // alias: x_bf dead after QKV GEMM

  hipMemsetAsync(loss, 0, 4, stream);
  cast_bf16_k<<<dim3((unsigned)(EL / 4 / 256)), 256, 0, stream>>>(x, x_bf, (int)(EL / 4));
  cast_bf16_k<<<dim3((unsigned)(EL / 4 / 256)), 256, 0, stream>>>(k_dino, kd_bf, (int)(EL / 4));
  transpose_cast_k<<<dim3(108, 36, 1), dim3(32, 8), 0, stream>>>(W_qkv, wqkvT, 1152, 3456);
  transpose_cast_k<<<dim3(36, 36, 1), dim3(32, 8), 0, stream>>>(W_proj, wprojT, 1152, 1152);
  transpose_cast_k<<<dim3(3, 32, 128), dim3(32, 8), 0, stream>>>(v_dino, vdT_bf, 1024, 72);
  gemm_bt_k<0><<<dim3(64, 27), 256, 0, stream>>>(x_bf, wqkvT, b_qkv, C_, q_bf, ks_bf, vsT_bf, nullptr, 0);
  attn_k<<<dim3(16, 128), 256, 0, stream>>>(q_bf, ks_bf, kd_bf, vsT_bf, vdT_bf, attn_bf, loss);
  gemm_bt_k<1><<<dim3(64, 9), 256, 0, stream>>>(attn_bf, wprojT, b_proj, C_, nullptr, nullptr, nullptr, out, C_);
  finalize_k<<<1, 64, 0, stream>>>(loss, out);
}